// Round 4
// baseline (57.026 us; speedup 1.0000x reference)
//
#include <hip/hip_runtime.h>

#define BB 4
#define DD 81
#define HH 256
#define WW 256
#define HW (HH*WW)
#define N4 (BB*HW/4)      // 65536 float4-outputs for cmin
#define SPLIT 9
#define CHUNK 9           // 9*9 = 81

// ---------------------------------------------------------------------------
// Kernel 1a: partial min over a 9-wide chunk of D.
// Explicit 9-deep register batch -> 9 loads in flight per thread (MLP).
// partial layout: [SPLIT][B*HW] floats, lives in the tail of d_out.
// ---------------------------------------------------------------------------
__global__ void k_cmin_part(const float* __restrict__ cost, float* __restrict__ partial) {
    int i = blockIdx.x * blockDim.x + threadIdx.x;   // [0, SPLIT*N4)
    if (i >= SPLIT * N4) return;
    int s   = i / N4;
    int r   = i - s * N4;            // float4 index within [B*HW/4]
    int b   = r / (HW / 4);
    int hw4 = r % (HW / 4);
    const float4* src = reinterpret_cast<const float4*>(cost + (size_t)b * DD * HW
                                                        + (size_t)(s * CHUNK) * HW) + hw4;
    float4 v[CHUNK];
    #pragma unroll
    for (int d = 0; d < CHUNK; ++d) v[d] = src[(size_t)d * (HW / 4)];
    // tree min over the 9 registers
    #pragma unroll
    for (int d = 1; d < CHUNK; ++d) {
        v[0].x = fminf(v[0].x, v[d].x);
        v[0].y = fminf(v[0].y, v[d].y);
        v[0].z = fminf(v[0].z, v[d].z);
        v[0].w = fminf(v[0].w, v[d].w);
    }
    reinterpret_cast<float4*>(partial)[i] = v[0];
}

// ---------------------------------------------------------------------------
// Kernel 1b: combine the 9 partials -> cmin
// ---------------------------------------------------------------------------
__global__ void k_combine(const float* __restrict__ partial, float* __restrict__ cmin) {
    int i = blockIdx.x * blockDim.x + threadIdx.x;   // [0, N4)
    if (i >= N4) return;
    const float4* p = reinterpret_cast<const float4*>(partial);
    float4 m = p[i];
    #pragma unroll
    for (int s = 1; s < SPLIT; ++s) {
        float4 v = p[(size_t)s * N4 + i];
        m.x = fminf(m.x, v.x);
        m.y = fminf(m.y, v.y);
        m.z = fminf(m.z, v.z);
        m.w = fminf(m.w, v.w);
    }
    reinterpret_cast<float4*>(cmin)[i] = m;
}

// ---------------------------------------------------------------------------
// Wave-parallel bidirectional linear-recurrence scan over 256 elements.
// m_j = c_j + e_j*m_{j-1}; operator (a,b) composes as cur∘prev =
// (a_c*a_p, a_c*b_p + b_c). g_j = e_j*m_{j-1} accumulated for both directions.
// ---------------------------------------------------------------------------
__device__ __forceinline__ void wave_scan_bidir(
        int lane, const float c[4], const float ef[4], const float eb[4], float g[4]) {
    float A = 1.f, B = 0.f;
    #pragma unroll
    for (int j = 0; j < 4; ++j) { B = ef[j] * B + c[j]; A = ef[j] * A; }
    #pragma unroll
    for (int d = 1; d < 64; d <<= 1) {
        float Ap = __shfl_up(A, d);
        float Bp = __shfl_up(B, d);
        if (lane >= d) { B = A * Bp + B; A = A * Ap; }
    }
    float m_in = __shfl_up(B, 1);
    if (lane == 0) m_in = 0.f;
    float m = m_in;
    #pragma unroll
    for (int j = 0; j < 4; ++j) { float t = ef[j] * m; g[j] = t; m = c[j] + t; }

    A = 1.f; B = 0.f;
    #pragma unroll
    for (int j = 3; j >= 0; --j) { B = eb[j] * B + c[j]; A = eb[j] * A; }
    #pragma unroll
    for (int d = 1; d < 64; d <<= 1) {
        float An = __shfl_down(A, d);
        float Bn = __shfl_down(B, d);
        if (lane + d < 64) { B = A * Bn + B; A = A * An; }
    }
    m_in = __shfl_down(B, 1);
    if (lane == 63) m_in = 0.f;
    m = m_in;
    #pragma unroll
    for (int j = 3; j >= 0; --j) { float t = eb[j] * m; g[j] += t; m = c[j] + t; }
}

// ---------------------------------------------------------------------------
// Kernel 2: waves [0,1024): horizontal rows (ch 0 fwd, ch 1 bwd) -> gh
//           waves [1024,2048): vertical cols (ch 2 down, ch 3 up) -> gv
// ---------------------------------------------------------------------------
__global__ void k_scan(const float* __restrict__ cmin, const float* __restrict__ edge,
                       float* __restrict__ gh, float* __restrict__ gv) {
    int tid  = blockIdx.x * blockDim.x + threadIdx.x;
    int wave = tid >> 6;
    int lane = tid & 63;
    float c[4], ef[4], eb[4], g[4];
    if (wave < BB * HH) {
        int b = wave / HH, h = wave % HH;
        size_t row = (size_t)b * HW + (size_t)h * WW;
        float4 c4  = reinterpret_cast<const float4*>(cmin + row)[lane];
        float4 f4  = reinterpret_cast<const float4*>(edge + ((size_t)b * 4 + 0) * HW + (size_t)h * WW)[lane];
        float4 b4  = reinterpret_cast<const float4*>(edge + ((size_t)b * 4 + 1) * HW + (size_t)h * WW)[lane];
        c[0]=c4.x; c[1]=c4.y; c[2]=c4.z; c[3]=c4.w;
        ef[0]=f4.x; ef[1]=f4.y; ef[2]=f4.z; ef[3]=f4.w;
        eb[0]=b4.x; eb[1]=b4.y; eb[2]=b4.z; eb[3]=b4.w;
        wave_scan_bidir(lane, c, ef, eb, g);
        float4 o = {g[0], g[1], g[2], g[3]};
        reinterpret_cast<float4*>(gh + row)[lane] = o;
    } else if (wave < 2 * BB * HH) {
        int wv = wave - BB * HH;
        int b = wv / WW, w = wv % WW;
        const float* cm = cmin + (size_t)b * HW + w;
        const float* e2 = edge + ((size_t)b * 4 + 2) * HW + w;
        const float* e3 = edge + ((size_t)b * 4 + 3) * HW + w;
        int r0 = lane * 4;
        #pragma unroll
        for (int j = 0; j < 4; ++j) {
            size_t off = (size_t)(r0 + j) * WW;
            c[j]  = cm[off];
            ef[j] = e2[off];
            eb[j] = e3[off];
        }
        wave_scan_bidir(lane, c, ef, eb, g);
        float* go = gv + (size_t)b * HW + w;
        #pragma unroll
        for (int j = 0; j < 4; ++j) go[(size_t)(r0 + j) * WW] = g[j];
    }
}

// ---------------------------------------------------------------------------
// Kernel 3: out[b,d,h,w] = 4*cost[b,d,h,w] + gh[b,h,w] + gv[b,h,w]
// ---------------------------------------------------------------------------
__global__ void k_out(const float* __restrict__ cost, const float* __restrict__ gh,
                      const float* __restrict__ gv, float* __restrict__ out) {
    int i = blockIdx.x * blockDim.x + threadIdx.x;
    const int n4 = BB * DD * HW / 4;
    if (i >= n4) return;
    int base = i << 2;
    int b    = base / (DD * HW);
    int rem  = base % (DD * HW);
    int hw   = rem % HW;
    float4 c = reinterpret_cast<const float4*>(cost)[i];
    int gi   = (b * HW + hw) >> 2;
    float4 a = reinterpret_cast<const float4*>(gh)[gi];
    float4 v = reinterpret_cast<const float4*>(gv)[gi];
    float4 o;
    o.x = 4.f * c.x + a.x + v.x;
    o.y = 4.f * c.y + a.y + v.y;
    o.z = 4.f * c.z + a.z + v.z;
    o.w = 4.f * c.w + a.w + v.w;
    reinterpret_cast<float4*>(out)[i] = o;
}

extern "C" void kernel_launch(void* const* d_in, const int* in_sizes, int n_in,
                              void* d_out, int out_size, void* d_ws, size_t ws_size,
                              hipStream_t stream) {
    const float* cost = (const float*)d_in[0];
    const float* edge = (const float*)d_in[1];
    float* out = (float*)d_out;

    // ws layout: gh [1MB] | gv [1MB] | cmin [1MB]
    float* gh   = (float*)d_ws;
    float* gv   = gh + (size_t)BB * HW;
    float* cmin = gv + (size_t)BB * HW;
    // partials [SPLIT][B*HW] (9 MB) live in the tail of d_out (dead space
    // until k_out rewrites the whole buffer at the end).
    float* partial = out + (size_t)out_size - (size_t)SPLIT * BB * HW;

    {   // 1a: partial mins, SPLIT*N4 = 589824 threads (2304 blocks)
        int n = SPLIT * N4;
        k_cmin_part<<<dim3((n + 255) / 256), dim3(256), 0, stream>>>(cost, partial);
    }
    {   // 1b: combine partials -> cmin
        k_combine<<<dim3((N4 + 255) / 256), dim3(256), 0, stream>>>(partial, cmin);
    }
    {   // 2: scans, 2048 waves = 131072 threads
        int n = 2 * BB * HH * 64;
        k_scan<<<dim3((n + 255) / 256), dim3(256), 0, stream>>>(cmin, edge, gh, gv);
    }
    {   // 3: output
        int n4 = BB * DD * HW / 4;
        k_out<<<dim3((n4 + 255) / 256), dim3(256), 0, stream>>>(cost, gh, gv, out);
    }
}